// Round 17
// baseline (72.805 us; speedup 1.0000x reference)
//
#include <hip/hip_runtime.h>

#define Bc 16
#define Hc 512
#define Wc 8192
#define NMAX 64
#define CPB 1024   // columns per block (256 threads x 4)
#define RPB 2      // rows per block  (R17 delta: was 4 — finest tail quantum)

typedef float f32x4 __attribute__((ext_vector_type(4)));
typedef f32x4 f32x4u __attribute__((aligned(4)));   // under-aligned load alias

// Fused kernel (R16 structure). Single delta vs R16: RPB 4 -> 2 (32768
// blocks, ~16 scheduling waves). Grid stays (x=rowchunk, y=colchunk, z=b):
// XCD = rowchunk%8 balanced, data-first launch order.
__global__ __launch_bounds__(256) void fused_compact_kernel(
    const float* __restrict__ x,
    const int* __restrict__ xi,    // (B, NMAX, 2) int32
    const int* __restrict__ Narr,  // (B,) int32
    const float* __restrict__ sep_param,
    float* __restrict__ out_x,     // (B, 1, H, W) float32
    float* __restrict__ out_xi)    // (B, NMAX, 2) as float32
{
    const int tid = threadIdx.x;
    const int rowchunk = blockIdx.x;   // 0..255 (XCD = rowchunk % 8)
    const int colchunk = blockIdx.y;   // 0..7   (data-first launch order)
    const int b = blockIdx.z;

    __shared__ int s_s[NMAX];
    __shared__ int s_sn[NMAX];
    __shared__ int s_en[NMAX];
    __shared__ int s_valid[NMAX];

    const int Nb = Narr[b];

    if (tid < NMAX) {   // entire first wave: tid == lane
        const int s = xi[b * NMAX * 2 + tid * 2 + 0];
        const int e = xi[b * NMAX * 2 + tid * 2 + 1];
        const int valid = (tid < Nb) ? 1 : 0;
        int w = e - s;
        if (w < 0) w = 0;
        if (!valid) w = 0;

        // inclusive prefix sum across the 64-lane wave
        int c = w;
        #pragma unroll
        for (int d = 1; d < 64; d <<= 1) {
            int t = __shfl_up(c, d);
            if (tid >= d) c += t;
        }
        s_s[tid] = s;
        s_valid[tid] = valid;
        s_sn[tid] = c - w + tid;
        s_en[tid] = c + tid;

        // xi_new output (once per batch)
        if (blockIdx.x == 0 && blockIdx.y == 0) {
            out_xi[b * NMAX * 2 + tid * 2 + 0] = valid ? (float)(c - w + tid) : 0.0f;
            out_xi[b * NMAX * 2 + tid * 2 + 1] = valid ? (float)(c + tid) : 0.0f;
        }
    }
    __syncthreads();

    // ---- per-thread column map (registers, computed once) ----
    const int col0 = colchunk * CPB + tid * 4;

    int m0, m1, m2, m3;
    {
        int mm[4];
        #pragma unroll
        for (int c = 0; c < 4; ++c) {
            const int col = col0 + c;
            // searchsorted(en, col, side='right')
            int lo = 0, hi = NMAX;
            while (lo < hi) {
                int mid = (lo + hi) >> 1;
                if (s_en[mid] > col) hi = mid; else lo = mid + 1;
            }
            int j = (lo < NMAX - 1) ? lo : (NMAX - 1);
            int v = -1;  // zero
            if (s_valid[j] && col >= s_sn[j] && col < s_en[j]) {
                int src = s_s[j] + (col - s_sn[j]);
                if (src < 0) src = 0;
                if (src > Wc - 1) src = Wc - 1;
                v = src;
            } else if (j >= 1) {
                int i = j - 1;
                if (s_valid[i] && (i < Nb - 1) && s_en[i] == col) v = -2;  // sep
            }
            mm[c] = v;
        }
        m0 = mm[0]; m1 = mm[1]; m2 = mm[2]; m3 = mm[3];
    }

    const long long base0 = ((long long)b * Hc + (long long)rowchunk * RPB) * (long long)Wc;

    // ---- wave-uniform zero fast path (the packed-right tail) ----
    const bool hasdata = (m0 != -1) | (m1 != -1) | (m2 != -1) | (m3 != -1);
    if (__ballot(hasdata) == 0ULL) {
        const f32x4 z = (f32x4){0.f, 0.f, 0.f, 0.f};
        #pragma unroll
        for (int rr = 0; rr < RPB; ++rr) {
            __builtin_nontemporal_store(
                z, (f32x4*)(out_x + base0 + (long long)rr * Wc + col0));
        }
        return;
    }

    // ---- data path ----
    const float sep = sep_param[0];

    const bool contig  = (m0 >= 0) & (m1 == m0 + 1) & (m2 == m0 + 2) & (m3 == m0 + 3);

    #pragma unroll
    for (int rr = 0; rr < RPB; ++rr) {
        const long long rowoff = base0 + (long long)rr * Wc;
        const float* __restrict__ xrow = x + rowoff;
        f32x4 v;
        if (contig) {
            // 4B-aligned vector load: legal on gfx950.
            v = *(const f32x4u*)(xrow + m0);
        } else {
            v.x = (m0 >= 0) ? xrow[m0] : ((m0 == -2) ? sep : 0.f);
            v.y = (m1 >= 0) ? xrow[m1] : ((m1 == -2) ? sep : 0.f);
            v.z = (m2 >= 0) ? xrow[m2] : ((m2 == -2) ? sep : 0.f);
            v.w = (m3 >= 0) ? xrow[m3] : ((m3 == -2) ? sep : 0.f);
        }
        __builtin_nontemporal_store(v, (f32x4*)(out_x + rowoff + col0));
    }
}

extern "C" void kernel_launch(void* const* d_in, const int* in_sizes, int n_in,
                              void* d_out, int out_size, void* d_ws, size_t ws_size,
                              hipStream_t stream) {
    const float* x   = (const float*)d_in[0];
    const int*   xi  = (const int*)d_in[1];
    const int*   N   = (const int*)d_in[2];
    const float* sep = (const float*)d_in[3];

    float* out_x  = (float*)d_out;
    float* out_xi = out_x + (long long)Bc * Hc * Wc;

    dim3 grid(Hc / RPB, Wc / CPB, Bc);   // (256, 8, 16) = 32768 blocks
    fused_compact_kernel<<<grid, 256, 0, stream>>>(x, xi, N, sep, out_x, out_xi);
}

// Round 18
// 54.230 us; speedup vs baseline: 1.3425x; 1.3425x over previous
//
#include <hip/hip_runtime.h>

#define Bc 16
#define Hc 512
#define Wc 8192
#define NMAX 64
#define CPB 1024   // columns per block (256 threads x 4)
#define RPB 4      // rows per block — measured optimum (16:59.7, 8:56.9, 4:54.7, 2:72.8 µs)

typedef float f32x4 __attribute__((ext_vector_type(4)));
typedef f32x4 f32x4u __attribute__((aligned(4)));   // under-aligned load alias

// FINAL (R16 best-known): fused compaction kernel.
//  - grid (x=rowchunk 128, y=colchunk 8, z=b): XCD = linear%8 = rowchunk%8 →
//    data/zero chunks balanced across XCDs; data-heavy colchunks launch first.
//  - per-block: first wave rebuilds the 64-block table via __shfl_up scan.
//  - per-thread 4-col map computed once into registers (binary search in LDS).
//  - wave-uniform ballot zero path: pure NT-fill for the packed-right tail.
//  - data path: unaligned 16B vector load for contiguous runs; scalar gather
//    at run edges; NT stores keep L2 clean for the gather-read stream.
__global__ __launch_bounds__(256) void fused_compact_kernel(
    const float* __restrict__ x,
    const int* __restrict__ xi,    // (B, NMAX, 2) int32
    const int* __restrict__ Narr,  // (B,) int32
    const float* __restrict__ sep_param,
    float* __restrict__ out_x,     // (B, 1, H, W) float32
    float* __restrict__ out_xi)    // (B, NMAX, 2) as float32
{
    const int tid = threadIdx.x;
    const int rowchunk = blockIdx.x;   // 0..127 (XCD = rowchunk % 8)
    const int colchunk = blockIdx.y;   // 0..7   (data-first launch order)
    const int b = blockIdx.z;

    __shared__ int s_s[NMAX];
    __shared__ int s_sn[NMAX];
    __shared__ int s_en[NMAX];
    __shared__ int s_valid[NMAX];

    const int Nb = Narr[b];

    if (tid < NMAX) {   // entire first wave: tid == lane
        const int s = xi[b * NMAX * 2 + tid * 2 + 0];
        const int e = xi[b * NMAX * 2 + tid * 2 + 1];
        const int valid = (tid < Nb) ? 1 : 0;
        int w = e - s;
        if (w < 0) w = 0;
        if (!valid) w = 0;

        // inclusive prefix sum across the 64-lane wave
        int c = w;
        #pragma unroll
        for (int d = 1; d < 64; d <<= 1) {
            int t = __shfl_up(c, d);
            if (tid >= d) c += t;
        }
        s_s[tid] = s;
        s_valid[tid] = valid;
        s_sn[tid] = c - w + tid;
        s_en[tid] = c + tid;

        // xi_new output (once per batch)
        if (blockIdx.x == 0 && blockIdx.y == 0) {
            out_xi[b * NMAX * 2 + tid * 2 + 0] = valid ? (float)(c - w + tid) : 0.0f;
            out_xi[b * NMAX * 2 + tid * 2 + 1] = valid ? (float)(c + tid) : 0.0f;
        }
    }
    __syncthreads();

    // ---- per-thread column map (registers, computed once) ----
    const int col0 = colchunk * CPB + tid * 4;

    int m0, m1, m2, m3;
    {
        int mm[4];
        #pragma unroll
        for (int c = 0; c < 4; ++c) {
            const int col = col0 + c;
            // searchsorted(en, col, side='right')
            int lo = 0, hi = NMAX;
            while (lo < hi) {
                int mid = (lo + hi) >> 1;
                if (s_en[mid] > col) hi = mid; else lo = mid + 1;
            }
            int j = (lo < NMAX - 1) ? lo : (NMAX - 1);
            int v = -1;  // zero
            if (s_valid[j] && col >= s_sn[j] && col < s_en[j]) {
                int src = s_s[j] + (col - s_sn[j]);
                if (src < 0) src = 0;
                if (src > Wc - 1) src = Wc - 1;
                v = src;
            } else if (j >= 1) {
                int i = j - 1;
                if (s_valid[i] && (i < Nb - 1) && s_en[i] == col) v = -2;  // sep
            }
            mm[c] = v;
        }
        m0 = mm[0]; m1 = mm[1]; m2 = mm[2]; m3 = mm[3];
    }

    const long long base0 = ((long long)b * Hc + (long long)rowchunk * RPB) * (long long)Wc;

    // ---- wave-uniform zero fast path (the packed-right tail) ----
    const bool hasdata = (m0 != -1) | (m1 != -1) | (m2 != -1) | (m3 != -1);
    if (__ballot(hasdata) == 0ULL) {
        const f32x4 z = (f32x4){0.f, 0.f, 0.f, 0.f};
        #pragma unroll
        for (int rr = 0; rr < RPB; ++rr) {
            __builtin_nontemporal_store(
                z, (f32x4*)(out_x + base0 + (long long)rr * Wc + col0));
        }
        return;
    }

    // ---- data path ----
    const float sep = sep_param[0];

    const bool contig  = (m0 >= 0) & (m1 == m0 + 1) & (m2 == m0 + 2) & (m3 == m0 + 3);

    #pragma unroll
    for (int rr = 0; rr < RPB; ++rr) {
        const long long rowoff = base0 + (long long)rr * Wc;
        const float* __restrict__ xrow = x + rowoff;
        f32x4 v;
        if (contig) {
            // 4B-aligned vector load: legal on gfx950.
            v = *(const f32x4u*)(xrow + m0);
        } else {
            v.x = (m0 >= 0) ? xrow[m0] : ((m0 == -2) ? sep : 0.f);
            v.y = (m1 >= 0) ? xrow[m1] : ((m1 == -2) ? sep : 0.f);
            v.z = (m2 >= 0) ? xrow[m2] : ((m2 == -2) ? sep : 0.f);
            v.w = (m3 >= 0) ? xrow[m3] : ((m3 == -2) ? sep : 0.f);
        }
        __builtin_nontemporal_store(v, (f32x4*)(out_x + rowoff + col0));
    }
}

extern "C" void kernel_launch(void* const* d_in, const int* in_sizes, int n_in,
                              void* d_out, int out_size, void* d_ws, size_t ws_size,
                              hipStream_t stream) {
    const float* x   = (const float*)d_in[0];
    const int*   xi  = (const int*)d_in[1];
    const int*   N   = (const int*)d_in[2];
    const float* sep = (const float*)d_in[3];

    float* out_x  = (float*)d_out;
    float* out_xi = out_x + (long long)Bc * Hc * Wc;

    dim3 grid(Hc / RPB, Wc / CPB, Bc);   // (128, 8, 16) = 16384 blocks
    fused_compact_kernel<<<grid, 256, 0, stream>>>(x, xi, N, sep, out_x, out_xi);
}